// Round 2
// baseline (175.541 us; speedup 1.0000x reference)
//
#include <hip/hip_runtime.h>

#define HEIGHT 8
#define H_FM 128
#define W_FM 128
#define C_FM 32

typedef float f32x4 __attribute__((ext_vector_type(4)));

// One thread = one (box, v, u, channel-group-of-4).
// Layout: tid = ((b*HEIGHT + v)*MW + u)*(C/4) + cg  -> out f32x4 at tid*4.
__global__ __launch_bounds__(256) void roi_rotate_kernel(
    const float* __restrict__ fm,      // (N, 128, 128, 32) f32
    const float* __restrict__ boxes,   // (B, 9) f32
    const int*   __restrict__ box_idx, // (B,) i32
    float*       __restrict__ out,     // crops (B,8,MW,32) then padded_width (B,)
    int B, int MW, float MWf)
{
    int tid = blockIdx.x * 256 + threadIdx.x;
    int cg  = tid & 7;          // channel group: c = cg*4
    int pix = tid >> 3;         // ((b*8 + v)*MW + u)
    int u   = pix % MW;
    int t2  = pix / MW;
    int v   = t2 & (HEIGHT - 1);
    int b   = t2 >> 3;
    if (b >= B) return;

    // Box parameters (uniform across 8*MW*8 threads; cached reads)
    const float* bx = boxes + b * 9;
    float x1 = bx[0] * 0.25f, y1 = bx[1] * 0.25f;
    float x2 = bx[2] * 0.25f, y2 = bx[3] * 0.25f;
    float x4 = bx[6] * 0.25f, y4 = bx[7] * 0.25f;

    float box_w = x2 - x1;
    float box_h = y4 - y1;
    float width = (float)HEIGHT * box_w / fmaxf(box_h, 1e-6f);
    width = fminf(fmaxf(width, 1.0f), MWf);

    float uf = (float)u;
    float tu = uf / width;
    float tv = (float)v * (1.0f / (float)HEIGHT);
    float sx = x1 + tu * (x2 - x1) + tv * (x4 - x1);
    float sy = y1 + tu * (y2 - y1) + tv * (y4 - y1);

    float x0f = floorf(sx), y0f = floorf(sy);
    float wx = sx - x0f,    wy = sy - y0f;   // reference: from UNclipped floor
    int x0i = min(max((int)x0f, 0), W_FM - 1);
    int x1i = min(x0i + 1, W_FM - 1);
    int y0i = min(max((int)y0f, 0), H_FM - 1);
    int y1i = min(y0i + 1, H_FM - 1);

    int bi = box_idx[b];
    const float* base = fm + (size_t)bi * (H_FM * W_FM * C_FM);
    int c = cg * 4;

    const f32x4 g00 = *(const f32x4*)(base + (y0i * W_FM + x0i) * C_FM + c);
    const f32x4 g01 = *(const f32x4*)(base + (y0i * W_FM + x1i) * C_FM + c);
    const f32x4 g10 = *(const f32x4*)(base + (y1i * W_FM + x0i) * C_FM + c);
    const f32x4 g11 = *(const f32x4*)(base + (y1i * W_FM + x1i) * C_FM + c);

    float w00 = (1.0f - wy) * (1.0f - wx);
    float w01 = (1.0f - wy) * wx;
    float w10 = wy * (1.0f - wx);
    float w11 = wy * wx;

    f32x4 r = w00 * g00 + w01 * g01 + w10 * g10 + w11 * g11;

    if (!(uf < width)) r = (f32x4)0.0f;

    // Write-once output: nontemporal so 134 MB of stores don't evict the
    // 16.8 MB feature map from L2.
    __builtin_nontemporal_store(r, (f32x4*)(out + (size_t)pix * C_FM + c));

    // One lane per box writes padded_width.
    if (u == 0 && v == 0 && cg == 0) {
        out[(size_t)B * HEIGHT * MW * C_FM + b] = MWf - width;
    }
}

extern "C" void kernel_launch(void* const* d_in, const int* in_sizes, int n_in,
                              void* d_out, int out_size, void* d_ws, size_t ws_size,
                              hipStream_t stream) {
    const float* fm    = (const float*)d_in[0];
    const float* boxes = (const float*)d_in[1];
    const int*   bidx  = (const int*)d_in[2];

    int B  = in_sizes[2];                              // 2048
    int MW = (out_size - B) / (B * HEIGHT * C_FM);     // 64

    int total  = B * HEIGHT * MW * (C_FM / 4);         // threads
    int blocks = (total + 255) / 256;

    roi_rotate_kernel<<<blocks, 256, 0, stream>>>(
        fm, boxes, bidx, (float*)d_out, B, MW, (float)MW);
}